// Round 5
// baseline (1938.874 us; speedup 1.0000x reference)
//
#include <hip/hip_runtime.h>
#include <hip/hip_bf16.h>

typedef unsigned int uint32;
typedef unsigned short ushort16;

#define N_MATN 100000
#define N_ELEMN 118
#define F_MATN 128
#define F_ELEMN 64
#define HIDN 128
#define NHEAD 8
#define OUTC 64
#define SCORE_BLOCKS 2048

__device__ __forceinline__ float blo(uint32 u){ return __uint_as_float(u << 16); }
__device__ __forceinline__ float bhi(uint32 u){ return __uint_as_float(u & 0xffff0000u); }
__device__ __forceinline__ ushort16 f2bf(float f){
    uint32 u = __float_as_uint(f);
    uint32 r = u + 0x7FFFu + ((u >> 16) & 1u);   // RNE
    return (ushort16)(r >> 16);
}

// ---------------- projection: elem nodes (118 x 64 f32 -> 118 x 128 bf16) + a_src_em dot
__global__ __launch_bounds__(128) void proj_elem_kernel(
    const float* __restrict__ x, const float* __restrict__ W,
    const float* __restrict__ bias, const float* __restrict__ a_se,
    ushort16* __restrict__ h, float* __restrict__ asrc_em)
{
    int c = threadIdx.x;
    float w[F_ELEMN];
    const float4* Wr = (const float4*)(W + c*F_ELEMN);
    #pragma unroll
    for(int i=0;i<16;i++){ float4 v=Wr[i]; w[4*i]=v.x; w[4*i+1]=v.y; w[4*i+2]=v.z; w[4*i+3]=v.w; }
    float bc = bias[c];
    float ac = a_se[c];
    for(int n=0;n<N_ELEMN;n++){
        const float4* xr = (const float4*)(x + n*F_ELEMN);
        float acc = 0.f;
        #pragma unroll
        for(int i=0;i<16;i++){
            float4 v = xr[i];
            acc += v.x*w[4*i+0] + v.y*w[4*i+1] + v.z*w[4*i+2] + v.w*w[4*i+3];
        }
        acc += bc;
        h[n*HIDN+c] = f2bf(acc);
        float p = acc*ac;
        #pragma unroll
        for(int m=8;m>=1;m>>=1) p += __shfl_xor(p, m, 16);
        if((c&15)==0) asrc_em[n*NHEAD + (c>>4)] = p;
    }
}

// ---------------- projection: mat nodes (100000 x 128 f32 -> bf16) + 3 alpha dots
__global__ __launch_bounds__(128) void proj_mat_kernel(
    const float* __restrict__ x, const float* __restrict__ W,
    const float* __restrict__ bias,
    const float* __restrict__ a_de, const float* __restrict__ a_sm, const float* __restrict__ a_dm,
    ushort16* __restrict__ h,
    float* __restrict__ adst_em, float* __restrict__ asrc_mm, float* __restrict__ adst_mm)
{
    int c = threadIdx.x;
    float w[F_MATN];
    const float4* Wr = (const float4*)(W + c*F_MATN);
    #pragma unroll
    for(int i=0;i<32;i++){ float4 v=Wr[i]; w[4*i]=v.x; w[4*i+1]=v.y; w[4*i+2]=v.z; w[4*i+3]=v.w; }
    float bc = bias[c];
    float ade = a_de[c], asm_ = a_sm[c], adm = a_dm[c];
    int hh = c >> 4;
    for(int n = blockIdx.x; n < N_MATN; n += gridDim.x){
        const float4* xr = (const float4*)(x + (size_t)n*F_MATN);
        float acc = 0.f;
        #pragma unroll
        for(int i=0;i<32;i++){
            float4 v = xr[i];            // all lanes same addr -> broadcast
            acc += v.x*w[4*i+0] + v.y*w[4*i+1] + v.z*w[4*i+2] + v.w*w[4*i+3];
        }
        acc += bc;
        h[(size_t)n*HIDN+c] = f2bf(acc);
        float p0 = acc*ade, p1 = acc*asm_, p2 = acc*adm;
        #pragma unroll
        for(int m=8;m>=1;m>>=1){
            p0 += __shfl_xor(p0, m, 16);
            p1 += __shfl_xor(p1, m, 16);
            p2 += __shfl_xor(p2, m, 16);
        }
        if((c&15)==0){
            adst_em[n*NHEAD+hh]=p0; asrc_mm[n*NHEAD+hh]=p1; adst_mm[n*NHEAD+hh]=p2;
        }
    }
}

// ---------------- CSR build
__global__ __launch_bounds__(256) void count_kernel(
    const int* __restrict__ dst, int nE, int* __restrict__ deg)
{
    int i = blockIdx.x*blockDim.x + threadIdx.x;
    int st = gridDim.x*blockDim.x;
    for(; i < nE; i += st) atomicAdd(&deg[dst[i]], 1);
}

__global__ __launch_bounds__(256) void scan_kernel(
    const int* __restrict__ deg, int* __restrict__ offs)
{
    __shared__ int part[256];
    int t = threadIdx.x;
    const int CH = (N_MATN + 255) >> 8;
    int beg = t*CH;
    int end = beg + CH; if(end > N_MATN) end = N_MATN;
    int s = 0;
    for(int i = beg; i < end; i++) s += deg[i];
    part[t] = s;
    __syncthreads();
    if(t == 0){
        int run = 0;
        for(int i = 0; i < 256; i++){ int v = part[i]; part[i] = run; run += v; }
    }
    __syncthreads();
    int run = part[t];
    for(int i = beg; i < end; i++){ offs[i] = run; run += deg[i]; }
    if(t == 255) offs[N_MATN] = run;
}

__global__ __launch_bounds__(256) void copy_kernel(
    const int* __restrict__ a, int* __restrict__ b, int n)
{
    int i = blockIdx.x*blockDim.x + threadIdx.x;
    int st = gridDim.x*blockDim.x;
    for(; i < n; i += st) b[i] = a[i];
}

__global__ __launch_bounds__(256) void scatter_kernel(
    const int* __restrict__ src, const int* __restrict__ dst, int nE,
    int* __restrict__ cur, int* __restrict__ csr)
{
    int i = blockIdx.x*blockDim.x + threadIdx.x;
    int st = gridDim.x*blockDim.x;
    for(; i < nE; i += st){
        int d = dst[i];
        int p = atomicAdd(&cur[d], 1);
        csr[p] = src[i];
    }
}

// ---------------- aggregation: one wave per dst node; softmax-weighted gather
__global__ __launch_bounds__(256) void agg_kernel(
    const int* __restrict__ offs, const int* __restrict__ csr,
    const ushort16* __restrict__ hsrc, const float* __restrict__ asrc,
    const float* __restrict__ adst, ushort16* __restrict__ o)
{
    int lane = threadIdx.x & 63;
    int w = (blockIdx.x*blockDim.x + threadIdx.x) >> 6;
    int nw = (gridDim.x*blockDim.x) >> 6;
    int hh = lane >> 3;                      // 8 lanes per head, 2 channels/lane
    for(int d = w; d < N_MATN; d += nw){
        int beg = offs[d], end = offs[d+1];
        float ad = adst[d*NHEAD + hh];
        float den = 0.f, n0 = 0.f, n1 = 0.f;
        for(int j = beg; j < end; j++){
            int s = csr[j];                  // wave-uniform broadcast load
            float al = asrc[s*NHEAD + hh] + ad;
            al = al > 0.f ? al : 0.2f*al;    // leaky_relu 0.2
            float ex = __expf(al);           // |al| <~ 5: no max-shift needed
            den += ex;                       // identical across each head's 8 lanes
            uint32 hv = ((const uint32*)hsrc)[s*64 + lane];
            n0 += blo(hv)*ex;
            n1 += bhi(hv)*ex;
        }
        float rdn = 1.0f/(den + 1e-16f);
        uint32 pk = (uint32)f2bf(fmaxf(n0*rdn, 0.f)) | ((uint32)f2bf(fmaxf(n1*rdn, 0.f)) << 16);
        ((uint32*)o)[(size_t)d*64 + lane] = pk;
    }
}

// ---------------- semantic scores: per-block partials (deterministic)
__global__ __launch_bounds__(128) void score_kernel(
    const ushort16* __restrict__ o_em, const ushort16* __restrict__ o_mm,
    const float* __restrict__ Wk, const float* __restrict__ bkv,
    const float* __restrict__ qv, float* __restrict__ partials)
{
    int c = threadIdx.x;
    float w[HIDN];
    const float4* Wr = (const float4*)(Wk + c*HIDN);
    #pragma unroll
    for(int i=0;i<32;i++){ float4 v=Wr[i]; w[4*i]=v.x; w[4*i+1]=v.y; w[4*i+2]=v.z; w[4*i+3]=v.w; }
    float bc = bkv[c], qc = qv[c];
    float se = 0.f, sm = 0.f;
    for(int n = blockIdx.x; n < N_MATN; n += gridDim.x){
        const uint4* er = (const uint4*)(o_em + (size_t)n*HIDN);
        const uint4* mr = (const uint4*)(o_mm + (size_t)n*HIDN);
        float ae = 0.f, am = 0.f;
        #pragma unroll
        for(int i=0;i<16;i++){
            uint4 ve = er[i], vm = mr[i];
            ae += blo(ve.x)*w[8*i+0] + bhi(ve.x)*w[8*i+1];
            am += blo(vm.x)*w[8*i+0] + bhi(vm.x)*w[8*i+1];
            ae += blo(ve.y)*w[8*i+2] + bhi(ve.y)*w[8*i+3];
            am += blo(vm.y)*w[8*i+2] + bhi(vm.y)*w[8*i+3];
            ae += blo(ve.z)*w[8*i+4] + bhi(ve.z)*w[8*i+5];
            am += blo(vm.z)*w[8*i+4] + bhi(vm.z)*w[8*i+5];
            ae += blo(ve.w)*w[8*i+6] + bhi(ve.w)*w[8*i+7];
            am += blo(vm.w)*w[8*i+6] + bhi(vm.w)*w[8*i+7];
        }
        se += qc * tanhf(bc + ae);
        sm += qc * tanhf(bc + am);
    }
    #pragma unroll
    for(int m=32;m>=1;m>>=1){ se += __shfl_xor(se,m); sm += __shfl_xor(sm,m); }
    __shared__ float red[4];
    int wv = c >> 6, ln = c & 63;
    if(ln==0){ red[wv*2]=se; red[wv*2+1]=sm; }
    __syncthreads();
    if(c==0){
        partials[blockIdx.x*2+0] = red[0]+red[2];
        partials[blockIdx.x*2+1] = red[1]+red[3];
    }
}

__global__ __launch_bounds__(256) void reduce_scores_kernel(
    const float* __restrict__ partials, float* __restrict__ scores)
{
    __shared__ float sh0[256], sh1[256];
    int t = threadIdx.x;
    float s0=0.f, s1=0.f;
    for(int i=t;i<SCORE_BLOCKS;i+=256){ s0 += partials[2*i]; s1 += partials[2*i+1]; }
    sh0[t]=s0; sh1[t]=s1; __syncthreads();
    for(int s=128;s>0;s>>=1){ if(t<s){ sh0[t]+=sh0[t+s]; sh1[t]+=sh1[t+s]; } __syncthreads(); }
    if(t==0){ scores[0]=sh0[0]; scores[1]=sh1[0]; }
}

// ---------------- final: out = (a0*o_em + a1*o_mm) @ Wl^T + bl  (FLOAT32 out)
__global__ __launch_bounds__(256) void final_kernel(
    const ushort16* __restrict__ o_em, const ushort16* __restrict__ o_mm,
    const float* __restrict__ Wl, const float* __restrict__ blv,
    const float* __restrict__ scores, float* __restrict__ out)
{
    int t = threadIdx.x;
    int j = t & 63, sub = t >> 6;
    float s0 = scores[0]*(1.0f/N_MATN), s1 = scores[1]*(1.0f/N_MATN);
    float mx = fmaxf(s0,s1);
    float e0 = __expf(s0-mx), e1 = __expf(s1-mx);
    float inv = 1.0f/(e0+e1);
    float a0 = e0*inv, a1 = e1*inv;
    float w[HIDN];
    const float4* Wr = (const float4*)(Wl + j*HIDN);
    #pragma unroll
    for(int i=0;i<32;i++){ float4 v=Wr[i]; w[4*i]=v.x; w[4*i+1]=v.y; w[4*i+2]=v.z; w[4*i+3]=v.w; }
    float bj = blv[j];
    for(int n = blockIdx.x*4 + sub; n < N_MATN; n += gridDim.x*4){
        const uint4* er = (const uint4*)(o_em + (size_t)n*HIDN);
        const uint4* mr = (const uint4*)(o_mm + (size_t)n*HIDN);
        float acc = 0.f;
        #pragma unroll
        for(int i=0;i<16;i++){
            uint4 ve = er[i], vm = mr[i];
            acc += (a0*blo(ve.x) + a1*blo(vm.x))*w[8*i+0];
            acc += (a0*bhi(ve.x) + a1*bhi(vm.x))*w[8*i+1];
            acc += (a0*blo(ve.y) + a1*blo(vm.y))*w[8*i+2];
            acc += (a0*bhi(ve.y) + a1*bhi(vm.y))*w[8*i+3];
            acc += (a0*blo(ve.z) + a1*blo(vm.z))*w[8*i+4];
            acc += (a0*bhi(ve.z) + a1*bhi(vm.z))*w[8*i+5];
            acc += (a0*blo(ve.w) + a1*blo(vm.w))*w[8*i+6];
            acc += (a0*bhi(ve.w) + a1*bhi(vm.w))*w[8*i+7];
        }
        out[(size_t)n*OUTC + j] = bj + acc;    // f32 store (reference output dtype)
    }
}

extern "C" void kernel_launch(void* const* d_in, const int* in_sizes, int n_in,
                              void* d_out, int out_size, void* d_ws, size_t ws_size,
                              hipStream_t stream)
{
    const float* x_mat    = (const float*)d_in[0];
    const float* x_elem   = (const float*)d_in[1];
    const float* W_pm     = (const float*)d_in[2];
    const float* b_pm     = (const float*)d_in[3];
    const float* W_pe     = (const float*)d_in[4];
    const float* b_pe     = (const float*)d_in[5];
    const float* a_se     = (const float*)d_in[6];
    const float* a_de     = (const float*)d_in[7];
    const float* a_sm     = (const float*)d_in[8];
    const float* a_dm     = (const float*)d_in[9];
    const float* Wk       = (const float*)d_in[10];
    const float* bk       = (const float*)d_in[11];
    const float* qv       = (const float*)d_in[12];
    const float* Wl       = (const float*)d_in[13];
    const float* bl       = (const float*)d_in[14];
    const int* src_em     = (const int*)d_in[15];
    const int* dst_em     = (const int*)d_in[16];
    const int* src_mm     = (const int*)d_in[17];
    const int* dst_mm     = (const int*)d_in[18];
    int nE_em = in_sizes[15];
    int nE_mm = in_sizes[17];

    char* ws = (char*)d_ws;
    size_t off = 0;
    auto alloc = [&](size_t bytes) -> void* {
        void* p = ws + off; off += (bytes + 255) & ~size_t(255); return p;
    };
    ushort16* h_mat   = (ushort16*)alloc((size_t)N_MATN*HIDN*2);   // 25.6 MB
    ushort16* h_elem  = (ushort16*)alloc((size_t)N_ELEMN*HIDN*2);
    float*    asrcEM  = (float*)   alloc((size_t)N_ELEMN*NHEAD*4);
    float*    adstEM  = (float*)   alloc((size_t)N_MATN*NHEAD*4);
    float*    asrcMM  = (float*)   alloc((size_t)N_MATN*NHEAD*4);
    float*    adstMM  = (float*)   alloc((size_t)N_MATN*NHEAD*4);
    int*      offs_em = (int*)     alloc((size_t)(N_MATN+1)*4);
    int*      offs_mm = (int*)     alloc((size_t)(N_MATN+1)*4);
    int*      csr_em  = (int*)     alloc((size_t)1000000*4);
    int*      csr_mm  = (int*)     alloc((size_t)2000000*4);
    ushort16* o_em    = (ushort16*)alloc((size_t)N_MATN*HIDN*2);   // 25.6 MB
    ushort16* o_mm    = (ushort16*)alloc((size_t)N_MATN*HIDN*2);   // 25.6 MB
    float*    partials= (float*)   alloc((size_t)SCORE_BLOCKS*2*4);
    float*    scores  = (float*)   alloc(256);
    size_t zero_start = off;
    int*      deg_em  = (int*)     alloc((size_t)N_MATN*4);
    int*      deg_mm  = (int*)     alloc((size_t)N_MATN*4);
    size_t zero_bytes = off - zero_start;

    hipMemsetAsync(ws + zero_start, 0, zero_bytes, stream);

    proj_elem_kernel<<<1, 128, 0, stream>>>(x_elem, W_pe, b_pe, a_se, h_elem, asrcEM);
    proj_mat_kernel<<<2048, 128, 0, stream>>>(x_mat, W_pm, b_pm, a_de, a_sm, a_dm,
                                              h_mat, adstEM, asrcMM, adstMM);

    count_kernel<<<1024, 256, 0, stream>>>(dst_em, nE_em, deg_em);
    count_kernel<<<1024, 256, 0, stream>>>(dst_mm, nE_mm, deg_mm);
    scan_kernel<<<1, 256, 0, stream>>>(deg_em, offs_em);
    scan_kernel<<<1, 256, 0, stream>>>(deg_mm, offs_mm);
    copy_kernel<<<256, 256, 0, stream>>>(offs_em, deg_em, N_MATN);
    copy_kernel<<<256, 256, 0, stream>>>(offs_mm, deg_mm, N_MATN);
    scatter_kernel<<<1024, 256, 0, stream>>>(src_em, dst_em, nE_em, deg_em, csr_em);
    scatter_kernel<<<1024, 256, 0, stream>>>(src_mm, dst_mm, nE_mm, deg_mm, csr_mm);

    agg_kernel<<<2048, 256, 0, stream>>>(offs_em, csr_em, h_elem, asrcEM, adstEM, o_em);
    agg_kernel<<<2048, 256, 0, stream>>>(offs_mm, csr_mm, h_mat, asrcMM, adstMM, o_mm);

    score_kernel<<<SCORE_BLOCKS, 128, 0, stream>>>(o_em, o_mm, Wk, bk, qv, partials);
    reduce_scores_kernel<<<1, 256, 0, stream>>>(partials, scores);
    final_kernel<<<2048, 256, 0, stream>>>(o_em, o_mm, Wl, bl, scores, (float*)d_out);
}